// Round 1
// baseline (198.046 us; speedup 1.0000x reference)
//
#include <hip/hip_runtime.h>

// Problem constants (from reference): B=64, L=550, D=768, R=3, p=50
#define BB 64
#define LL 550
#define DD 768
#define RR 3
#define PP 50
#define LEN_KEEP 400   // L - R*p = 550 - 150

// Output layout in d_out (flat, return order, all read back as float32):
//   [0]                       x_masked  : B*LEN_KEEP*D = 19,660,800 floats
//   [O_MASK]                  mask      : B*L          =     35,200 floats
//   [O_RESTORE]               ids_restore (stored as float values)
#define O_MASK     (BB * LEN_KEEP * DD)
#define O_RESTORE  (O_MASK + BB * LL)

// Kernel 1: one block per batch. Stable-ascending rank via O(L^2) count.
// rank[i] = #{ j : v[j] < v[i]  ||  (v[j]==v[i] && j<i) }
// This reproduces jnp.argsort (stable) + inverse permutation exactly:
//   ids_restore[i] = rank[i];  mask[i] = rank[i] >= LEN_KEEP.
__global__ __launch_bounds__(576) void rank_kernel(
    const float* __restrict__ noise,
    const int*   __restrict__ indexes,
    float*       __restrict__ out,
    int*         __restrict__ ws_rank)
{
    __shared__ float s_noise[LL];
    const int b = blockIdx.x;
    const int t = threadIdx.x;

    if (t < LL) s_noise[t] = noise[b * LL + t];
    __syncthreads();

    // Apply masking: noise[idx*50 .. idx*50+50) = 2.0.
    // Duplicate indexes write the same value -> benign race.
    if (t < RR * PP) {
        const int r   = t / PP;
        const int idx = indexes[b * RR + r];
        s_noise[idx * PP + (t % PP)] = 2.0f;
    }
    __syncthreads();

    if (t < LL) {
        const float v = s_noise[t];
        int rank = 0;
        #pragma unroll 10
        for (int j = 0; j < LL; ++j) {
            const float vj = s_noise[j];            // LDS broadcast (conflict-free)
            rank += (vj < v) || (vj == v && j < t); // stable tie-break by index
        }
        out[O_MASK    + b * LL + t] = (rank >= LEN_KEEP) ? 1.0f : 0.0f;
        out[O_RESTORE + b * LL + t] = (float)rank;
        ws_rank[b * LL + t] = rank;
    }
}

// Kernel 2: one block per (batch, source row). Kept rows (rank < 400) are
// copied x[b,i,:] -> x_masked[b,rank,:] as float4 (192 lanes * 16B = 3KB row).
__global__ __launch_bounds__(DD / 4) void gather_kernel(
    const float* __restrict__ x,
    const int*   __restrict__ ws_rank,
    float*       __restrict__ out)
{
    const int i = blockIdx.x;   // source row in [0, L)
    const int b = blockIdx.y;   // batch
    const int r = ws_rank[b * LL + i];
    if (r >= LEN_KEEP) return;  // dropped row

    const float4* __restrict__ src =
        (const float4*)(x + ((size_t)b * LL + i) * DD);
    float4* __restrict__ dst =
        (float4*)(out + ((size_t)b * LEN_KEEP + r) * DD);
    dst[threadIdx.x] = src[threadIdx.x];
}

extern "C" void kernel_launch(void* const* d_in, const int* in_sizes, int n_in,
                              void* d_out, int out_size, void* d_ws, size_t ws_size,
                              hipStream_t stream)
{
    const float* x       = (const float*)d_in[0];  // (64, 550, 768) f32
    const float* noise   = (const float*)d_in[1];  // (64, 550) f32
    const int*   indexes = (const int*)  d_in[2];  // (64, 3) int32
    float*       out     = (float*)d_out;
    int*         ws_rank = (int*)d_ws;             // 64*550 ints = 140,800 B

    rank_kernel<<<BB, 576, 0, stream>>>(noise, indexes, out, ws_rank);

    dim3 grid(LL, BB);
    gather_kernel<<<grid, DD / 4, 0, stream>>>(x, ws_rank, out);
}

// Round 2
// 193.644 us; speedup vs baseline: 1.0227x; 1.0227x over previous
//
#include <hip/hip_runtime.h>

// Problem constants (from reference): B=64, L=550, D=768, R=3, p=50
#define BB 64
#define LL 550
#define DD 768
#define RR 3
#define PP 50
#define LEN_KEEP 400         // L - R*p
#define CHUNK 192            // rows ranked per block in rank_kernel
#define NCHUNK 3             // ceil(550/192)
#define L4 138               // ceil(550/4) float4 groups (550 = 137*4 + 2)

// Output layout in d_out (flat, return order, read back as float32):
//   [0]         x_masked    : B*LEN_KEEP*D
//   [O_MASK]    mask        : B*L
//   [O_RESTORE] ids_restore : B*L (stored as float values; exact for <2^24)
#define O_MASK     (BB * LEN_KEEP * DD)
#define O_RESTORE  (O_MASK + BB * LL)

// Kernel 1: stable ascending rank without sorting.
// rank[i] = #{ j : v[j] < v[i] || (v[j]==v[i] && j<i) }  == ids_restore[i].
// Grid (3, 64): each block loads the full masked noise row into LDS, ranks a
// 192-row chunk. LDS reads are float4 same-address broadcasts (conflict-free,
// ~3 cyc/elem on the LDS pipe vs 5.8 for b32).
// Also emits the compacted dest->src map for the gather kernel.
__global__ __launch_bounds__(CHUNK) void rank_kernel(
    const float* __restrict__ noise,
    const int*   __restrict__ indexes,
    float*       __restrict__ out,
    int*         __restrict__ src_of)   // [B][LEN_KEEP] source row per dest row
{
    __shared__ __align__(16) float s_noise[L4 * 4];  // 552, padded
    const int b = blockIdx.y;
    const int c = blockIdx.x;
    const int t = threadIdx.x;

    for (int j = t; j < LL; j += CHUNK) s_noise[j] = noise[b * LL + j];
    if (t < L4 * 4 - LL) s_noise[LL + t] = 1e30f;    // pad: never < or == v
    __syncthreads();

    // noise[idx*50 .. idx*50+50) = 2.0 ; duplicate idx -> same value, benign.
    if (t < RR * PP) {
        const int idx = indexes[b * RR + t / PP];
        s_noise[idx * PP + (t % PP)] = 2.0f;
    }
    __syncthreads();

    const int i = c * CHUNK + t;
    if (i < LL) {
        const float v = s_noise[i];
        const float4* __restrict__ s4 = (const float4*)s_noise;
        int rank = 0;
        #pragma unroll 6
        for (int j4 = 0; j4 < L4; ++j4) {
            const float4 f = s4[j4];                 // LDS b128 broadcast
            const int j = j4 * 4;
            rank += (f.x < v) || (f.x == v && (j + 0) < i);
            rank += (f.y < v) || (f.y == v && (j + 1) < i);
            rank += (f.z < v) || (f.z == v && (j + 2) < i);
            rank += (f.w < v) || (f.w == v && (j + 3) < i);
        }
        out[O_MASK    + b * LL + i] = (rank >= LEN_KEEP) ? 1.0f : 0.0f;
        out[O_RESTORE + b * LL + i] = (float)rank;
        if (rank < LEN_KEEP) src_of[b * LEN_KEEP + rank] = i;  // each dest once
    }
}

// Kernel 2: destination-indexed row gather. Grid (400, 64), one block per
// output row -> no wasted blocks, writes are perfectly sequential across the
// grid; reads are row-contiguous 3 KB chunks. 192 lanes x float4 = 768 floats.
__global__ __launch_bounds__(DD / 4) void gather_kernel(
    const float* __restrict__ x,
    const int*   __restrict__ src_of,
    float*       __restrict__ out)
{
    const int d = blockIdx.x;   // dest row in [0, LEN_KEEP)
    const int b = blockIdx.y;
    const int i = src_of[b * LEN_KEEP + d];

    const float4* __restrict__ src =
        (const float4*)(x + ((size_t)b * LL + i) * DD);
    float4* __restrict__ dst =
        (float4*)(out + ((size_t)b * LEN_KEEP + d) * DD);
    dst[threadIdx.x] = src[threadIdx.x];
}

extern "C" void kernel_launch(void* const* d_in, const int* in_sizes, int n_in,
                              void* d_out, int out_size, void* d_ws, size_t ws_size,
                              hipStream_t stream)
{
    const float* x       = (const float*)d_in[0];  // (64, 550, 768) f32
    const float* noise   = (const float*)d_in[1];  // (64, 550) f32
    const int*   indexes = (const int*)  d_in[2];  // (64, 3) int32
    float*       out     = (float*)d_out;
    int*         src_of  = (int*)d_ws;             // 64*400 ints = 102,400 B

    dim3 rgrid(NCHUNK, BB);
    rank_kernel<<<rgrid, CHUNK, 0, stream>>>(noise, indexes, out, src_of);

    dim3 ggrid(LEN_KEEP, BB);
    gather_kernel<<<ggrid, DD / 4, 0, stream>>>(x, src_of, out);
}